// Round 17
// baseline (416.528 us; speedup 1.0000x reference)
//
#include <hip/hip_runtime.h>

typedef __bf16 bf16;
typedef __bf16 bf16x8 __attribute__((ext_vector_type(8)));
typedef __bf16 bf16x4 __attribute__((ext_vector_type(4)));
typedef float f32x4 __attribute__((ext_vector_type(4)));
typedef unsigned int u32;
typedef unsigned short u16;

#define MFMA_BF16 __builtin_amdgcn_mfma_f32_16x16x32_bf16

#define GLOAD_LDS(g, l)                                        \
  __builtin_amdgcn_global_load_lds(                            \
      (__attribute__((address_space(1))) void*)(g),            \
      (__attribute__((address_space(3))) void*)(l), 16, 0, 0)

// ---------------------------------------------------------------- utilities
__global__ void cvt_f32_bf16(const float* __restrict__ in, bf16* __restrict__ out, int n) {
  int i = (blockIdx.x * blockDim.x + threadIdx.x) * 4;
  if (i >= n) return;
  float4 v = *(const float4*)(in + i);
  bf16x4 o;
  o[0] = (bf16)v.x; o[1] = (bf16)v.y; o[2] = (bf16)v.z; o[3] = (bf16)v.w;
  *(bf16x4*)(out + i) = o;
}

// W [K][N] fp32 -> Wt [N][K] bf16
__global__ void transpose_w(const float* __restrict__ w, bf16* __restrict__ wt, int K, int N) {
  __shared__ float tile[32][33];
  int n0 = blockIdx.x * 32, k0 = blockIdx.y * 32;
  int t = threadIdx.x;
  int c = t & 31, r = t >> 5;
#pragma unroll
  for (int i = 0; i < 4; i++)
    tile[r + i * 8][c] = w[(size_t)(k0 + r + i * 8) * N + n0 + c];
  __syncthreads();
#pragma unroll
  for (int i = 0; i < 4; i++)
    wt[(size_t)(n0 + r + i * 8) * K + k0 + c] = (bf16)tile[c][r + i * 8];
}

__device__ inline float gelu_exact(float x) {
  return 0.5f * x * (1.0f + erff(x * 0.70710678118654752f));
}

// ---------------------------------------------------------------- GEMM
// R12 structure verbatim (best measured: ff1 113us, FETCH 50MB, 0 confl).
template <int MODE, int WTM>
__global__ __launch_bounds__(256, (WTM == 128) ? 2 : 4) void gemm_bt(
    const bf16* __restrict__ A, const bf16* __restrict__ Bt,
    bf16* __restrict__ outb, float* __restrict__ outf,
    const float* __restrict__ residf, const bf16* __restrict__ residb,
    int K, int N) {
  constexpr int BM = WTM * 2;
  constexpr int MR = WTM / 16;
  __shared__ __align__(16) bf16 As[2][BM * 32];
  __shared__ __align__(16) bf16 Bs[2][128 * 32];
  const int tid = threadIdx.x;
  const int lane = tid & 63, w = tid >> 6;
  const int g = lane >> 4, l15 = lane & 15;
  const int wm = w >> 1, wn = w & 1;

  const int NT = N >> 7;
  const int nsupN = NT >> 2;
  const int cpx = (int)gridDim.x >> 3;
  const int widx = ((int)blockIdx.x & 7) * cpx + ((int)blockIdx.x >> 3);
  const int s = widx >> 4, r4 = widx & 15;
  const int sm = s / nsupN, sn = s - sm * nsupN;
  const int m0 = (sm * 4 + (r4 & 3)) * BM;
  const int n0 = (sn * 4 + (r4 >> 2)) * 128;

  f32x4 acc[MR][4] = {};

  const int srow = tid >> 2;
  const int schunk = (tid & 3) ^ ((tid >> 3) & 3);
  const char* gA = (const char*)A;
  const char* gB = (const char*)Bt;
  const size_t aOff = ((size_t)(m0 + srow) * K + schunk * 8) * 2;
  const size_t bOff = ((size_t)(n0 + srow) * K + schunk * 8) * 2;

  auto stage = [&](int kt, int slot) {
    const size_t kb = (size_t)kt * 64;
#pragma unroll
    for (int i = 0; i < BM / 64; i++)
      GLOAD_LDS(gA + aOff + (size_t)(i * 64) * K * 2 + kb,
                &As[slot][(i * 64 + w * 16) * 32]);
#pragma unroll
    for (int i = 0; i < 2; i++)
      GLOAD_LDS(gB + bOff + (size_t)(i * 64) * K * 2 + kb,
                &Bs[slot][(i * 64 + w * 16) * 32]);
  };

  const int rsw = (g ^ ((l15 >> 1) & 3)) << 4;
  const int rdA = (wm * WTM + l15) * 64 + rsw;
  const int rdB = (wn * 64 + l15) * 64 + rsw;

  const int T = K >> 5;
  stage(0, 0);

  int slot = 0;
  for (int t = 0; t < T; ++t) {
    __syncthreads();
    if (t + 1 < T) stage(t + 1, slot ^ 1);
    const char* pA = (const char*)As[slot];
    const char* pB = (const char*)Bs[slot];
    bf16x8 a[MR], b[4];
#pragma unroll
    for (int mi = 0; mi < MR; mi++) a[mi] = *(const bf16x8*)(pA + rdA + mi * 1024);
#pragma unroll
    for (int ni = 0; ni < 4; ni++) b[ni] = *(const bf16x8*)(pB + rdB + ni * 1024);
    __builtin_amdgcn_s_setprio(1);
#pragma unroll
    for (int mi = 0; mi < MR; mi++)
#pragma unroll
      for (int ni = 0; ni < 4; ni++)
        acc[mi][ni] = MFMA_BF16(a[mi], b[ni], acc[mi][ni], 0, 0, 0);
    __builtin_amdgcn_s_setprio(0);
    slot ^= 1;
  }

  const int row_base = m0 + wm * WTM;
  const int col_base = n0 + wn * 64 + l15;
#pragma unroll
  for (int mi = 0; mi < MR; mi++)
#pragma unroll
    for (int ni = 0; ni < 4; ni++) {
      const int c = col_base + ni * 16;
#pragma unroll
      for (int r = 0; r < 4; r++) {
        const int row = row_base + mi * 16 + 4 * g + r;
        const size_t idx = (size_t)row * N + c;
        float v = acc[mi][ni][r];
        if constexpr (MODE == 0) {
          outb[idx] = (bf16)v;
        } else if constexpr (MODE == 1) {
          outb[idx] = (bf16)(v + residf[idx]);
        } else if constexpr (MODE == 2) {
          outb[idx] = (bf16)gelu_exact(v);
        } else {
          outf[idx] = v + (float)residb[idx];
        }
      }
    }
}

// ---------------------------------------------------------------- attention
// BQ=256: wave owns 32 q-rows as TWO 16-row frags (A,B) sharing every
// K/V LDS fragment read -> LDS bytes per MFMA halved (was the measured
// bottleneck: 160KB/block-step vs 16 MFMA/wave). Per step now 32 MFMA/wave
// on the same 16KB of reads. Pairing bx & 7-bx (q-tiles of 256) keeps 36
// uniform steps; grid 64x4 = 256 blocks = 1/CU all-resident. Staging,
// swizzles, permuted-K QK^T, lazy defer-max softmax as R12.
__global__ __launch_bounds__(512, 2) void attn_fwd(const bf16* __restrict__ qkv,
                                                   bf16* __restrict__ O) {
  __shared__ __align__(16) char Kl[2][64 * 128];
  __shared__ __align__(16) char Vt[2][64 * 128];
  const int tid = threadIdx.x;
  const int lane = tid & 63, w = tid >> 6;
  const int g = lane >> 4, l15 = lane & 15;
  const int bh = blockIdx.x;
  const int bx = blockIdx.y;
  const int b = bh >> 4, hh = bh & 15;
  const size_t tokbase = (size_t)b * 2048;

  const bf16* kbase = qkv + tokbase * 3072 + 1024 + hh * 64;
  const bf16* vbase = qkv + tokbase * 3072 + 2048 + hh * 64;
  const int kperm = 8 * (l15 >> 2) + (l15 & 3);

  const bool vstage = tid < 256;
  const int t2 = tid & 255;
  const int vrg = t2 >> 4, vds = (t2 & 15) * 4;
  const int krow = t2 >> 2, ksl = t2 & 3;
  const int kswzr = (krow & 3) | ((krow & 8) >> 1);

  union U4 { ushort4 v; u16 a[4]; };
  U4 vr[4];
  uint4 kpr0, kpr1;

  auto prefetch = [&](int k0n) {
    if (vstage) {
#pragma unroll
      for (int i4 = 0; i4 < 4; i4++)
        vr[i4].v = *(const ushort4*)(vbase + (size_t)(k0n + 4 * vrg + i4) * 3072 + vds);
    } else {
      const bf16* kp = kbase + (size_t)(k0n + krow) * 3072 + 8 * ksl;
      kpr0 = *(const uint4*)(kp);
      kpr1 = *(const uint4*)(kp + 32);
    }
  };

  prefetch(0);
  int cur = 0;

  for (int half = 0; half < 2; half++) {
    const int xT = half ? (7 - bx) : bx;
    const int q0 = xT * 256;
    const int qw0 = q0 + 32 * w;          // wave's 32 q-rows
    const int qiA = qw0 + l15;
    const int qiB = qw0 + 16 + l15;
    const int kend = q0 + 256;

    const bf16* qpA = qkv + (tokbase + qw0 + l15) * 3072 + hh * 64 + 8 * g;
    const bf16x8 qfA0 = *(const bf16x8*)(qpA);
    const bf16x8 qfA1 = *(const bf16x8*)(qpA + 32);
    const bf16* qpB = qpA + (size_t)16 * 3072;
    const bf16x8 qfB0 = *(const bf16x8*)(qpB);
    const bf16x8 qfB1 = *(const bf16x8*)(qpB + 32);

    f32x4 otA[4] = {}, otB[4] = {};
    float mA = -INFINITY, lA = 0.0f, mB = -INFINITY, lB = 0.0f;

    for (int k0 = 0; k0 < kend; k0 += 64) {
      char* Kc = Kl[cur];
      char* Vc = Vt[cur];
      if (vstage) {
#pragma unroll
        for (int dj = 0; dj < 4; dj++) {
          const int d = vds + dj;
          u32 lo = (u32)vr[0].a[dj] | ((u32)vr[1].a[dj] << 16);
          u32 hi2 = (u32)vr[2].a[dj] | ((u32)vr[3].a[dj] << 16);
          const int boff = d * 128 + ((((vrg >> 1) ^ ((d >> 1) & 7)) << 4)) + ((vrg & 1) << 3);
          *(uint2*)(Vc + boff) = make_uint2(lo, hi2);
        }
      } else {
        *(uint4*)(Kc + krow * 128 + ((ksl ^ kswzr) << 4)) = kpr0;
        *(uint4*)(Kc + krow * 128 + (((ksl | 4) ^ kswzr) << 4)) = kpr1;
      }
      __syncthreads();

      const int k0n = (k0 + 64 < kend) ? k0 + 64 : 0;
      prefetch(k0n);

      if (k0 <= qw0 + 31) {  // frag B (rows qw0+16..31) active at least
        const bool aAct = (k0 <= qw0 + 15);
        const bool lastTA = (k0 + 63 > qw0);
        const bool lastTB = (k0 + 63 > qw0 + 16);
        const int npB = lastTB ? (((qw0 + 31 - k0) >> 5) + 1) : 2;
        const int npA = aAct ? (lastTA ? (((qw0 + 15 - k0) >> 5) + 1) : 2) : 0;

        // ---- QK^T: ka/kb loaded ONCE, used by both frags
        f32x4 stA[4], stB[4];
#pragma unroll
        for (int ip = 0; ip < 2; ip++)
          if (ip < npB) {
#pragma unroll
            for (int h2 = 0; h2 < 2; h2++) {
              const int kr = 32 * ip + 4 * h2 + kperm;
              const int swzk = (kr & 3) | ((kr & 8) >> 1);
              const char* kro = Kc + kr * 128;
              bf16x8 ka = *(const bf16x8*)(kro + ((g ^ swzk) << 4));
              bf16x8 kb = *(const bf16x8*)(kro + (((g | 4) ^ swzk) << 4));
              f32x4 z = {};
              z = MFMA_BF16(ka, qfB0, z, 0, 0, 0);
              stB[2 * ip + h2] = MFMA_BF16(kb, qfB1, z, 0, 0, 0);
              if (ip < npA) {
                f32x4 z2 = {};
                z2 = MFMA_BF16(ka, qfA0, z2, 0, 0, 0);
                stA[2 * ip + h2] = MFMA_BF16(kb, qfA1, z2, 0, 0, 0);
              }
            }
          }

        // ---- masks + lane-local max
        float pA[4][4], pB[4][4];
        float mtA = -INFINITY, mtB = -INFINITY;
#pragma unroll
        for (int ip = 0; ip < 2; ip++)
          if (ip < npB) {
#pragma unroll
            for (int h2 = 0; h2 < 2; h2++)
#pragma unroll
              for (int r = 0; r < 4; r++) {
                const int kk = k0 + 32 * ip + 8 * g + 4 * h2 + r;
                float v = (float)stB[2 * ip + h2][r] * 0.125f;
                if (lastTB && kk > qiB) v = -INFINITY;
                pB[2 * ip + h2][r] = v;
                mtB = fmaxf(mtB, v);
                if (ip < npA) {
                  float va = (float)stA[2 * ip + h2][r] * 0.125f;
                  if (lastTA && kk > qiA) va = -INFINITY;
                  pA[2 * ip + h2][r] = va;
                  mtA = fmaxf(mtA, va);
                }
              }
          }

        // ---- lazy defer-max (combined branch, per-frag rescale)
        float exc = mtB - mB;
        if (npA) exc = fmaxf(exc, mtA - mA);
        if (!__all(exc <= 8.0f)) {
          float rB = fmaxf(mtB, __shfl_xor(mtB, 16, 64));
          rB = fmaxf(rB, __shfl_xor(rB, 32, 64));
          const float mBn = fmaxf(mB, rB);
          const float alB = __expf(mB - mBn);
          lB *= alB;
#pragma unroll
          for (int dt = 0; dt < 4; dt++)
#pragma unroll
            for (int r = 0; r < 4; r++) otB[dt][r] *= alB;
          mB = mBn;
          if (npA) {
            float rA = fmaxf(mtA, __shfl_xor(mtA, 16, 64));
            rA = fmaxf(rA, __shfl_xor(rA, 32, 64));
            const float mAn = fmaxf(mA, rA);
            const float alA = __expf(mA - mAn);
            lA *= alA;
#pragma unroll
            for (int dt = 0; dt < 4; dt++)
#pragma unroll
              for (int r = 0; r < 4; r++) otA[dt][r] *= alA;
            mA = mAn;
          }
        }

        // ---- exp + partial sums
        float sB = 0.0f, sA = 0.0f;
#pragma unroll
        for (int ip = 0; ip < 2; ip++)
          if (ip < npB) {
#pragma unroll
            for (int h2 = 0; h2 < 2; h2++)
#pragma unroll
              for (int r = 0; r < 4; r++) {
                float e = __expf(pB[2 * ip + h2][r] - mB);
                pB[2 * ip + h2][r] = e;
                sB += e;
                if (ip < npA) {
                  float ea = __expf(pA[2 * ip + h2][r] - mA);
                  pA[2 * ip + h2][r] = ea;
                  sA += ea;
                }
              }
          }
        lB += sB;
        lA += sA;

        // ---- PV: vf loaded ONCE per (ip,dt), used by both frags
#pragma unroll
        for (int ip = 0; ip < 2; ip++)
          if (ip < npB) {
            bf16x8 pfB, pfA;
#pragma unroll
            for (int h2 = 0; h2 < 2; h2++)
#pragma unroll
              for (int r = 0; r < 4; r++) {
                pfB[4 * h2 + r] = (bf16)pB[2 * ip + h2][r];
                if (ip < npA) pfA[4 * h2 + r] = (bf16)pA[2 * ip + h2][r];
              }
#pragma unroll
            for (int dt = 0; dt < 4; dt++) {
              const bf16x8 vf = *(const bf16x8*)(
                  Vc + (dt * 16 + l15) * 128 + (((4 * ip + g) ^ (l15 >> 1)) << 4));
              otB[dt] = MFMA_BF16(vf, pfB, otB[dt], 0, 0, 0);
              if (ip < npA) otA[dt] = MFMA_BF16(vf, pfA, otA[dt], 0, 0, 0);
            }
          }
      }
      cur ^= 1;
    }

    // ---- epilogue (frag A rows qw0+l15, frag B rows qw0+16+l15)
    {
      float l = lA + __shfl_xor(lA, 16, 64);
      l += __shfl_xor(l, 32, 64);
      const float inv = 1.0f / l;
      bf16* obase = O + (tokbase + qw0 + l15) * 1024 + hh * 64;
#pragma unroll
      for (int dt = 0; dt < 4; dt++) {
        bf16x4 ov;
#pragma unroll
        for (int r = 0; r < 4; r++) ov[r] = (bf16)(otA[dt][r] * inv);
        *(bf16x4*)(obase + dt * 16 + 4 * g) = ov;
      }
    }
    {
      float l = lB + __shfl_xor(lB, 16, 64);
      l += __shfl_xor(l, 32, 64);
      const float inv = 1.0f / l;
      bf16* obase = O + (tokbase + qw0 + 16 + l15) * 1024 + hh * 64;
#pragma unroll
      for (int dt = 0; dt < 4; dt++) {
        bf16x4 ov;
#pragma unroll
        for (int r = 0; r < 4; r++) ov[r] = (bf16)(otB[dt][r] * inv);
        *(bf16x4*)(obase + dt * 16 + 4 * g) = ov;
      }
    }
  }
}

// ---------------------------------------------------------------- launch
extern "C" void kernel_launch(void* const* d_in, const int* in_sizes, int n_in,
                              void* d_out, int out_size, void* d_ws, size_t ws_size,
                              hipStream_t stream) {
  const float* x = (const float*)d_in[0];
  const float* w_qkv = (const float*)d_in[1];
  const float* w_out = (const float*)d_in[2];
  const float* w_ff1 = (const float*)d_in[3];
  const float* w_ff2 = (const float*)d_in[4];
  float* out = (float*)d_out;

  char* ws = (char*)d_ws;
  size_t off = 0;
  auto alloc = [&](size_t bytes) {
    void* p = ws + off;
    off += (bytes + 255) & ~(size_t)255;
    return p;
  };
  const size_t M = 8192;
  bf16* X16   = (bf16*)alloc(M * 1024 * 2);
  bf16* WqkvT = (bf16*)alloc(3072ull * 1024 * 2);
  bf16* WoutT = (bf16*)alloc(1024ull * 1024 * 2);
  bf16* Wff1T = (bf16*)alloc(4096ull * 1024 * 2);
  bf16* Wff2T = (bf16*)alloc(1024ull * 4096 * 2);
  bf16* QKV   = (bf16*)alloc(M * 3072 * 2);
  bf16* Obuf  = (bf16*)alloc(M * 1024 * 2);
  bf16* x1b   = (bf16*)alloc(M * 1024 * 2);
  bf16* Hbuf  = (bf16*)alloc(M * 4096 * 2);

  cvt_f32_bf16<<<8192, 256, 0, stream>>>(x, X16, 8192 * 1024);
  transpose_w<<<dim3(3072 / 32, 1024 / 32), 256, 0, stream>>>(w_qkv, WqkvT, 1024, 3072);
  transpose_w<<<dim3(1024 / 32, 1024 / 32), 256, 0, stream>>>(w_out, WoutT, 1024, 1024);
  transpose_w<<<dim3(4096 / 32, 1024 / 32), 256, 0, stream>>>(w_ff1, Wff1T, 1024, 4096);
  transpose_w<<<dim3(1024 / 32, 4096 / 32), 256, 0, stream>>>(w_ff2, Wff2T, 4096, 1024);

  gemm_bt<0, 128><<<32 * 24, 256, 0, stream>>>(X16, WqkvT, QKV, nullptr, nullptr, nullptr, 1024, 3072);
  attn_fwd<<<dim3(64, 4), 512, 0, stream>>>(QKV, Obuf);
  gemm_bt<1, 64><<<64 * 8, 256, 0, stream>>>(Obuf, WoutT, x1b, nullptr, x, nullptr, 1024, 1024);
  gemm_bt<2, 128><<<32 * 32, 256, 0, stream>>>(x1b, Wff1T, Hbuf, nullptr, nullptr, nullptr, 1024, 4096);
  gemm_bt<3, 64><<<64 * 8, 256, 0, stream>>>(Hbuf, Wff2T, nullptr, out, nullptr, x1b, 4096, 1024);
}

// Round 18
// 380.386 us; speedup vs baseline: 1.0950x; 1.0950x over previous
//
#include <hip/hip_runtime.h>

typedef __bf16 bf16;
typedef __bf16 bf16x8 __attribute__((ext_vector_type(8)));
typedef __bf16 bf16x4 __attribute__((ext_vector_type(4)));
typedef float f32x4 __attribute__((ext_vector_type(4)));
typedef unsigned int u32;
typedef unsigned short u16;

#define MFMA_BF16 __builtin_amdgcn_mfma_f32_16x16x32_bf16

#define GLOAD_LDS(g, l)                                        \
  __builtin_amdgcn_global_load_lds(                            \
      (__attribute__((address_space(1))) void*)(g),            \
      (__attribute__((address_space(3))) void*)(l), 16, 0, 0)

// ---------------------------------------------------------------- utilities
__global__ void cvt_f32_bf16(const float* __restrict__ in, bf16* __restrict__ out, int n) {
  int i = (blockIdx.x * blockDim.x + threadIdx.x) * 4;
  if (i >= n) return;
  float4 v = *(const float4*)(in + i);
  bf16x4 o;
  o[0] = (bf16)v.x; o[1] = (bf16)v.y; o[2] = (bf16)v.z; o[3] = (bf16)v.w;
  *(bf16x4*)(out + i) = o;
}

// W [K][N] fp32 -> Wt [N][K] bf16
__global__ void transpose_w(const float* __restrict__ w, bf16* __restrict__ wt, int K, int N) {
  __shared__ float tile[32][33];
  int n0 = blockIdx.x * 32, k0 = blockIdx.y * 32;
  int t = threadIdx.x;
  int c = t & 31, r = t >> 5;
#pragma unroll
  for (int i = 0; i < 4; i++)
    tile[r + i * 8][c] = w[(size_t)(k0 + r + i * 8) * N + n0 + c];
  __syncthreads();
#pragma unroll
  for (int i = 0; i < 4; i++)
    wt[(size_t)(n0 + r + i * 8) * K + k0 + c] = (bf16)tile[c][r + i * 8];
}

__device__ inline float gelu_exact(float x) {
  return 0.5f * x * (1.0f + erff(x * 0.70710678118654752f));
}

// ---------------------------------------------------------------- GEMM
// R12 structure verbatim (best measured: ff1 113us, FETCH 50MB, 0 confl).
// MODE 0 additionally pre-scales the Q columns (n0 < 1024) by 0.125 —
// power-of-two => bit-identical bf16, removes attn's per-step scale muls.
template <int MODE, int WTM>
__global__ __launch_bounds__(256, (WTM == 128) ? 2 : 4) void gemm_bt(
    const bf16* __restrict__ A, const bf16* __restrict__ Bt,
    bf16* __restrict__ outb, float* __restrict__ outf,
    const float* __restrict__ residf, const bf16* __restrict__ residb,
    int K, int N) {
  constexpr int BM = WTM * 2;
  constexpr int MR = WTM / 16;
  __shared__ __align__(16) bf16 As[2][BM * 32];
  __shared__ __align__(16) bf16 Bs[2][128 * 32];
  const int tid = threadIdx.x;
  const int lane = tid & 63, w = tid >> 6;
  const int g = lane >> 4, l15 = lane & 15;
  const int wm = w >> 1, wn = w & 1;

  const int NT = N >> 7;
  const int nsupN = NT >> 2;
  const int cpx = (int)gridDim.x >> 3;
  const int widx = ((int)blockIdx.x & 7) * cpx + ((int)blockIdx.x >> 3);
  const int s = widx >> 4, r4 = widx & 15;
  const int sm = s / nsupN, sn = s - sm * nsupN;
  const int m0 = (sm * 4 + (r4 & 3)) * BM;
  const int n0 = (sn * 4 + (r4 >> 2)) * 128;

  f32x4 acc[MR][4] = {};

  const int srow = tid >> 2;
  const int schunk = (tid & 3) ^ ((tid >> 3) & 3);
  const char* gA = (const char*)A;
  const char* gB = (const char*)Bt;
  const size_t aOff = ((size_t)(m0 + srow) * K + schunk * 8) * 2;
  const size_t bOff = ((size_t)(n0 + srow) * K + schunk * 8) * 2;

  auto stage = [&](int kt, int slot) {
    const size_t kb = (size_t)kt * 64;
#pragma unroll
    for (int i = 0; i < BM / 64; i++)
      GLOAD_LDS(gA + aOff + (size_t)(i * 64) * K * 2 + kb,
                &As[slot][(i * 64 + w * 16) * 32]);
#pragma unroll
    for (int i = 0; i < 2; i++)
      GLOAD_LDS(gB + bOff + (size_t)(i * 64) * K * 2 + kb,
                &Bs[slot][(i * 64 + w * 16) * 32]);
  };

  const int rsw = (g ^ ((l15 >> 1) & 3)) << 4;
  const int rdA = (wm * WTM + l15) * 64 + rsw;
  const int rdB = (wn * 64 + l15) * 64 + rsw;

  const int T = K >> 5;
  stage(0, 0);

  int slot = 0;
  for (int t = 0; t < T; ++t) {
    __syncthreads();
    if (t + 1 < T) stage(t + 1, slot ^ 1);
    const char* pA = (const char*)As[slot];
    const char* pB = (const char*)Bs[slot];
    bf16x8 a[MR], b[4];
#pragma unroll
    for (int mi = 0; mi < MR; mi++) a[mi] = *(const bf16x8*)(pA + rdA + mi * 1024);
#pragma unroll
    for (int ni = 0; ni < 4; ni++) b[ni] = *(const bf16x8*)(pB + rdB + ni * 1024);
    __builtin_amdgcn_s_setprio(1);
#pragma unroll
    for (int mi = 0; mi < MR; mi++)
#pragma unroll
      for (int ni = 0; ni < 4; ni++)
        acc[mi][ni] = MFMA_BF16(a[mi], b[ni], acc[mi][ni], 0, 0, 0);
    __builtin_amdgcn_s_setprio(0);
    slot ^= 1;
  }

  const float qsc = (MODE == 0 && n0 < 1024) ? 0.125f : 1.0f;
  const int row_base = m0 + wm * WTM;
  const int col_base = n0 + wn * 64 + l15;
#pragma unroll
  for (int mi = 0; mi < MR; mi++)
#pragma unroll
    for (int ni = 0; ni < 4; ni++) {
      const int c = col_base + ni * 16;
#pragma unroll
      for (int r = 0; r < 4; r++) {
        const int row = row_base + mi * 16 + 4 * g + r;
        const size_t idx = (size_t)row * N + c;
        float v = acc[mi][ni][r];
        if constexpr (MODE == 0) {
          outb[idx] = (bf16)(v * qsc);
        } else if constexpr (MODE == 1) {
          outb[idx] = (bf16)(v + residf[idx]);
        } else if constexpr (MODE == 2) {
          outb[idx] = (bf16)gelu_exact(v);
        } else {
          outf[idx] = v + (float)residb[idx];
        }
      }
    }
}

// ---------------------------------------------------------------- attention
// R12 structure (512 thr, BQ=128, paired q-tiles two-pass, K+V^T LDS dbuf,
// single barrier/step, permuted-K QK^T, lazy defer-max softmax) with:
//  (a) Q pre-scaled in qkv epilogue -> no *0.125f here;
//  (b) causal mask under a wave-uniform `if (lastT)` branch (rare);
//  (c) K staged via global_load_lds: pre-swizzled per-lane SOURCE, linear
//      LDS dest (byte-identical layout to the old reg-staged path) — 8 DMA
//      instrs replace 512 reg-loads + 512 ds_writes per block-step.
__global__ __launch_bounds__(512, 2) void attn_fwd(const bf16* __restrict__ qkv,
                                                   bf16* __restrict__ O) {
  __shared__ __align__(16) char Kl[2][64 * 128];
  __shared__ __align__(16) char Vt[2][64 * 128];
  const int tid = threadIdx.x;
  const int lane = tid & 63, w = tid >> 6;
  const int g = lane >> 4, l15 = lane & 15;
  const int bh = blockIdx.x;
  const int bx = blockIdx.y;
  const int b = bh >> 4, hh = bh & 15;
  const size_t tokbase = (size_t)b * 2048;

  const bf16* kbase = qkv + tokbase * 3072 + 1024 + hh * 64;
  const bf16* vbase = qkv + tokbase * 3072 + 2048 + hh * 64;
  const int kperm = 8 * (l15 >> 2) + (l15 & 3);

  // K DMA mapping: thread t covers K row tid>>3, 16B chunk tid&7,
  // source chunk pre-XORed with the read swizzle (involution).
  const int kr8 = tid >> 3, kc = tid & 7;
  const int kswz = (kr8 & 3) | ((kr8 & 8) >> 1);
  const bf16* kSrc = kbase + (size_t)kr8 * 3072 + 8 * (kc ^ kswz);

  // V staging role (threads < 256): 4x4 in-register transpose
  const bool vstage = tid < 256;
  const int t2 = tid & 255;
  const int vrg = t2 >> 4, vds = (t2 & 15) * 4;

  union U4 { ushort4 v; u16 a[4]; };
  U4 vr[4];

  auto prefetchV = [&](int k0n) {
    if (vstage) {
#pragma unroll
      for (int i4 = 0; i4 < 4; i4++)
        vr[i4].v = *(const ushort4*)(vbase + (size_t)(k0n + 4 * vrg + i4) * 3072 + vds);
    }
  };
  auto gloadK = [&](int k0n, int buf) {
    GLOAD_LDS(kSrc + (size_t)k0n * 3072, Kl[buf] + w * 1024);
  };

  prefetchV(0);
  gloadK(0, 0);
  int cur = 0;

  for (int half = 0; half < 2; half++) {
    const int xT = half ? (15 - bx) : bx;
    const int q0 = xT * 128;
    const int qw0 = q0 + 16 * w;
    const int qi = qw0 + l15;
    const int kend = q0 + 128;

    const bf16* qptr = qkv + (tokbase + qw0 + l15) * 3072 + hh * 64 + 8 * g;
    const bf16x8 qf0 = *(const bf16x8*)(qptr);
    const bf16x8 qf1 = *(const bf16x8*)(qptr + 32);

    f32x4 ot[4] = {};
    float m_i = -INFINITY, l_i = 0.0f;

    for (int k0 = 0; k0 < kend; k0 += 64) {
      char* Kc = Kl[cur];
      char* Vc = Vt[cur];
      if (vstage) {
#pragma unroll
        for (int dj = 0; dj < 4; dj++) {
          const int d = vds + dj;
          u32 lo = (u32)vr[0].a[dj] | ((u32)vr[1].a[dj] << 16);
          u32 hi2 = (u32)vr[2].a[dj] | ((u32)vr[3].a[dj] << 16);
          const int boff = d * 128 + ((((vrg >> 1) ^ ((d >> 1) & 7)) << 4)) + ((vrg & 1) << 3);
          *(uint2*)(Vc + boff) = make_uint2(lo, hi2);
        }
      }
      __syncthreads();  // drains gloadK(k0) + orders V writes

      const int k0n = (k0 + 64 < kend) ? k0 + 64 : 0;
      prefetchV(k0n);
      gloadK(k0n, cur ^ 1);

      if (k0 <= qw0 + 15) {
        const bool lastT = (k0 + 63 > qw0);
        const int npair = lastT ? (((qw0 + 15 - k0) >> 5) + 1) : 2;

        f32x4 st[4];
#pragma unroll
        for (int ip = 0; ip < 2; ip++)
          if (ip < npair) {
#pragma unroll
            for (int h2 = 0; h2 < 2; h2++) {
              const int kr = 32 * ip + 4 * h2 + kperm;
              const int swzk = (kr & 3) | ((kr & 8) >> 1);
              const char* kro = Kc + kr * 128;
              bf16x8 ka = *(const bf16x8*)(kro + ((g ^ swzk) << 4));
              bf16x8 kb = *(const bf16x8*)(kro + (((g | 4) ^ swzk) << 4));
              f32x4 z = {};
              z = MFMA_BF16(ka, qf0, z, 0, 0, 0);
              st[2 * ip + h2] = MFMA_BF16(kb, qf1, z, 0, 0, 0);
            }
          }

        // p = scores (Q pre-scaled); mask only in the rare lastT step
        float p[4][4];
#pragma unroll
        for (int ip = 0; ip < 2; ip++)
          if (ip < npair)
#pragma unroll
            for (int h2 = 0; h2 < 2; h2++)
#pragma unroll
              for (int r = 0; r < 4; r++)
                p[2 * ip + h2][r] = (float)st[2 * ip + h2][r];
        if (lastT) {
#pragma unroll
          for (int ip = 0; ip < 2; ip++)
            if (ip < npair)
#pragma unroll
              for (int h2 = 0; h2 < 2; h2++)
#pragma unroll
                for (int r = 0; r < 4; r++) {
                  const int kk = k0 + 32 * ip + 8 * g + 4 * h2 + r;
                  if (kk > qi) p[2 * ip + h2][r] = -INFINITY;
                }
        }
        float mt = -INFINITY;
#pragma unroll
        for (int ip = 0; ip < 2; ip++)
          if (ip < npair)
#pragma unroll
            for (int h2 = 0; h2 < 2; h2++)
#pragma unroll
              for (int r = 0; r < 4; r++) mt = fmaxf(mt, p[2 * ip + h2][r]);

        if (!__all(mt - m_i <= 8.0f)) {
          mt = fmaxf(mt, __shfl_xor(mt, 16, 64));
          mt = fmaxf(mt, __shfl_xor(mt, 32, 64));
          const float m_new = fmaxf(m_i, mt);
          const float alpha = __expf(m_i - m_new);
          l_i *= alpha;
#pragma unroll
          for (int dt = 0; dt < 4; dt++)
#pragma unroll
            for (int r = 0; r < 4; r++) ot[dt][r] *= alpha;
          m_i = m_new;
        }
        float sum = 0.0f;
#pragma unroll
        for (int ip = 0; ip < 2; ip++)
          if (ip < npair) {
#pragma unroll
            for (int h2 = 0; h2 < 2; h2++)
#pragma unroll
              for (int r = 0; r < 4; r++) {
                float e = __expf(p[2 * ip + h2][r] - m_i);
                p[2 * ip + h2][r] = e;
                sum += e;
              }
          }
        l_i += sum;

#pragma unroll
        for (int ip = 0; ip < 2; ip++)
          if (ip < npair) {
            bf16x8 pf;
#pragma unroll
            for (int h2 = 0; h2 < 2; h2++)
#pragma unroll
              for (int r = 0; r < 4; r++) pf[4 * h2 + r] = (bf16)p[2 * ip + h2][r];
#pragma unroll
            for (int dt = 0; dt < 4; dt++) {
              const bf16x8 vf = *(const bf16x8*)(
                  Vc + (dt * 16 + l15) * 128 + (((4 * ip + g) ^ (l15 >> 1)) << 4));
              ot[dt] = MFMA_BF16(vf, pf, ot[dt], 0, 0, 0);
            }
          }
      }
      cur ^= 1;
    }

    l_i += __shfl_xor(l_i, 16, 64);
    l_i += __shfl_xor(l_i, 32, 64);
    const float inv = 1.0f / l_i;
    bf16* obase = O + (tokbase + qw0 + l15) * 1024 + hh * 64;
#pragma unroll
    for (int dt = 0; dt < 4; dt++) {
      bf16x4 ov;
#pragma unroll
      for (int r = 0; r < 4; r++) ov[r] = (bf16)(ot[dt][r] * inv);
      *(bf16x4*)(obase + dt * 16 + 4 * g) = ov;
    }
  }
}

// ---------------------------------------------------------------- launch
extern "C" void kernel_launch(void* const* d_in, const int* in_sizes, int n_in,
                              void* d_out, int out_size, void* d_ws, size_t ws_size,
                              hipStream_t stream) {
  const float* x = (const float*)d_in[0];
  const float* w_qkv = (const float*)d_in[1];
  const float* w_out = (const float*)d_in[2];
  const float* w_ff1 = (const float*)d_in[3];
  const float* w_ff2 = (const float*)d_in[4];
  float* out = (float*)d_out;

  char* ws = (char*)d_ws;
  size_t off = 0;
  auto alloc = [&](size_t bytes) {
    void* p = ws + off;
    off += (bytes + 255) & ~(size_t)255;
    return p;
  };
  const size_t M = 8192;
  bf16* X16   = (bf16*)alloc(M * 1024 * 2);
  bf16* WqkvT = (bf16*)alloc(3072ull * 1024 * 2);
  bf16* WoutT = (bf16*)alloc(1024ull * 1024 * 2);
  bf16* Wff1T = (bf16*)alloc(4096ull * 1024 * 2);
  bf16* Wff2T = (bf16*)alloc(1024ull * 4096 * 2);
  bf16* QKV   = (bf16*)alloc(M * 3072 * 2);
  bf16* Obuf  = (bf16*)alloc(M * 1024 * 2);
  bf16* x1b   = (bf16*)alloc(M * 1024 * 2);
  bf16* Hbuf  = (bf16*)alloc(M * 4096 * 2);

  cvt_f32_bf16<<<8192, 256, 0, stream>>>(x, X16, 8192 * 1024);
  transpose_w<<<dim3(3072 / 32, 1024 / 32), 256, 0, stream>>>(w_qkv, WqkvT, 1024, 3072);
  transpose_w<<<dim3(1024 / 32, 1024 / 32), 256, 0, stream>>>(w_out, WoutT, 1024, 1024);
  transpose_w<<<dim3(4096 / 32, 1024 / 32), 256, 0, stream>>>(w_ff1, Wff1T, 1024, 4096);
  transpose_w<<<dim3(1024 / 32, 4096 / 32), 256, 0, stream>>>(w_ff2, Wff2T, 4096, 1024);

  gemm_bt<0, 128><<<32 * 24, 256, 0, stream>>>(X16, WqkvT, QKV, nullptr, nullptr, nullptr, 1024, 3072);
  attn_fwd<<<dim3(64, 8), 512, 0, stream>>>(QKV, Obuf);
  gemm_bt<1, 64><<<64 * 8, 256, 0, stream>>>(Obuf, WoutT, x1b, nullptr, x, nullptr, 1024, 1024);
  gemm_bt<2, 128><<<32 * 32, 256, 0, stream>>>(x1b, Wff1T, Hbuf, nullptr, nullptr, nullptr, 1024, 4096);
  gemm_bt<3, 64><<<64 * 8, 256, 0, stream>>>(Hbuf, Wff2T, nullptr, out, nullptr, x1b, 4096, 1024);
}

// Round 19
// 358.004 us; speedup vs baseline: 1.1635x; 1.0625x over previous
//
#include <hip/hip_runtime.h>

typedef __bf16 bf16;
typedef __bf16 bf16x8 __attribute__((ext_vector_type(8)));
typedef __bf16 bf16x4 __attribute__((ext_vector_type(4)));
typedef float f32x4 __attribute__((ext_vector_type(4)));
typedef unsigned int u32;
typedef unsigned short u16;

#define MFMA_BF16 __builtin_amdgcn_mfma_f32_16x16x32_bf16

#define GLOAD_LDS(g, l)                                        \
  __builtin_amdgcn_global_load_lds(                            \
      (__attribute__((address_space(1))) void*)(g),            \
      (__attribute__((address_space(3))) void*)(l), 16, 0, 0)

// ---------------------------------------------------------------- utilities
__global__ void cvt_f32_bf16(const float* __restrict__ in, bf16* __restrict__ out, int n) {
  int i = (blockIdx.x * blockDim.x + threadIdx.x) * 4;
  if (i >= n) return;
  float4 v = *(const float4*)(in + i);
  bf16x4 o;
  o[0] = (bf16)v.x; o[1] = (bf16)v.y; o[2] = (bf16)v.z; o[3] = (bf16)v.w;
  *(bf16x4*)(out + i) = o;
}

// W [K][N] fp32 -> Wt [N][K] bf16
__global__ void transpose_w(const float* __restrict__ w, bf16* __restrict__ wt, int K, int N) {
  __shared__ float tile[32][33];
  int n0 = blockIdx.x * 32, k0 = blockIdx.y * 32;
  int t = threadIdx.x;
  int c = t & 31, r = t >> 5;
#pragma unroll
  for (int i = 0; i < 4; i++)
    tile[r + i * 8][c] = w[(size_t)(k0 + r + i * 8) * N + n0 + c];
  __syncthreads();
#pragma unroll
  for (int i = 0; i < 4; i++)
    wt[(size_t)(n0 + r + i * 8) * K + k0 + c] = (bf16)tile[c][r + i * 8];
}

__device__ inline float gelu_exact(float x) {
  return 0.5f * x * (1.0f + erff(x * 0.70710678118654752f));
}

// ---------------------------------------------------------------- GEMM
// m97-EXACT geometry + verified fixes: 128x128 tile, BK=32, 256 thr =
// 4 waves (2Mx2N, wave tile 64x64, acc[4][4] = 64 AGPR ~ 164 total regs),
// SINGLE-buffered 16KB LDS, 2 barriers/step (sync -> stage -> sync ->
// compute), __launch_bounds__(256,3) => THREE blocks/CU — the m97-measured
// occupancy (912 TF) that every 2-block variant since R10 lacked. Staging
// keeps R12's 0-conflict XOR swizzle (inverse on per-lane global source,
// linear LDS dest) and the supertile XCD L2 ordering (FETCH ~ideal).
// MODE 0 pre-scales Q columns (n0 < 1024) by 0.125 (exact in bf16).
template <int MODE>
__global__ __launch_bounds__(256, 3) void gemm_bt(
    const bf16* __restrict__ A, const bf16* __restrict__ Bt,
    bf16* __restrict__ outb, float* __restrict__ outf,
    const float* __restrict__ residf, const bf16* __restrict__ residb,
    int K, int N) {
  __shared__ __align__(16) bf16 As[128 * 32];
  __shared__ __align__(16) bf16 Bs[128 * 32];
  const int tid = threadIdx.x;
  const int lane = tid & 63, w = tid >> 6;
  const int g = lane >> 4, l15 = lane & 15;
  const int wm = w >> 1, wn = w & 1;

  // ---- XCD chunk + supertile decode (4M x 4N tile supertiles, m fastest)
  const int NT = N >> 7;
  const int nsupN = NT >> 2;
  const int cpx = (int)gridDim.x >> 3;
  const int widx = ((int)blockIdx.x & 7) * cpx + ((int)blockIdx.x >> 3);
  const int s = widx >> 4, r4 = widx & 15;
  const int sm = s / nsupN, sn = s - sm * nsupN;
  const int m0 = (sm * 4 + (r4 & 3)) * 128;
  const int n0 = (sn * 4 + (r4 >> 2)) * 128;

  f32x4 acc[4][4] = {};

  // staging: thread -> row tid>>2 (64 rows/issue-set), 16B chunk (tid&3),
  // chunk pre-swizzled with the inverse of the read swizzle.
  const int srow = tid >> 2;
  const int schunk = (tid & 3) ^ ((tid >> 3) & 3);
  const char* gA = (const char*)A;
  const char* gB = (const char*)Bt;
  const size_t aOff = ((size_t)(m0 + srow) * K + schunk * 8) * 2;
  const size_t bOff = ((size_t)(n0 + srow) * K + schunk * 8) * 2;

  auto stage = [&](int kt) {
    const size_t kb = (size_t)kt * 64;  // kt*32 elems * 2B
#pragma unroll
    for (int i = 0; i < 2; i++)
      GLOAD_LDS(gA + aOff + (size_t)(i * 64) * K * 2 + kb,
                &As[(i * 64 + w * 16) * 32]);
#pragma unroll
    for (int i = 0; i < 2; i++)
      GLOAD_LDS(gB + bOff + (size_t)(i * 64) * K * 2 + kb,
                &Bs[(i * 64 + w * 16) * 32]);
  };

  // read offsets (bytes): row*64 + swizzled 16B chunk
  const int rsw = (g ^ ((l15 >> 1) & 3)) << 4;
  const int rdA = (wm * 64 + l15) * 64 + rsw;
  const int rdB = (wn * 64 + l15) * 64 + rsw;

  const int T = K >> 5;
  for (int t = 0; t < T; ++t) {
    __syncthreads();  // all waves done reading previous tile (WAR)
    stage(t);
    __syncthreads();  // vmcnt(0) drain -> buffer ready (hidden by 2 other blocks)
    const char* pA = (const char*)As;
    const char* pB = (const char*)Bs;
    bf16x8 a[4], b[4];
#pragma unroll
    for (int mi = 0; mi < 4; mi++) a[mi] = *(const bf16x8*)(pA + rdA + mi * 1024);
#pragma unroll
    for (int ni = 0; ni < 4; ni++) b[ni] = *(const bf16x8*)(pB + rdB + ni * 1024);
    __builtin_amdgcn_s_setprio(1);
#pragma unroll
    for (int mi = 0; mi < 4; mi++)
#pragma unroll
      for (int ni = 0; ni < 4; ni++)
        acc[mi][ni] = MFMA_BF16(a[mi], b[ni], acc[mi][ni], 0, 0, 0);
    __builtin_amdgcn_s_setprio(0);
  }

  const float qsc = (MODE == 0 && n0 < 1024) ? 0.125f : 1.0f;
  const int row_base = m0 + wm * 64;
  const int col_base = n0 + wn * 64 + l15;
#pragma unroll
  for (int mi = 0; mi < 4; mi++)
#pragma unroll
    for (int ni = 0; ni < 4; ni++) {
      const int c = col_base + ni * 16;
#pragma unroll
      for (int r = 0; r < 4; r++) {
        const int row = row_base + mi * 16 + 4 * g + r;
        const size_t idx = (size_t)row * N + c;
        float v = acc[mi][ni][r];
        if constexpr (MODE == 0) {
          outb[idx] = (bf16)(v * qsc);
        } else if constexpr (MODE == 1) {
          outb[idx] = (bf16)(v + residf[idx]);
        } else if constexpr (MODE == 2) {
          outb[idx] = (bf16)gelu_exact(v);
        } else {
          outf[idx] = v + (float)residb[idx];
        }
      }
    }
}

// ---------------------------------------------------------------- attention
// R18 version verbatim: 512 thr, BQ=128, paired q-tiles two-pass, V^T
// reg-transposed + K via global_load_lds (pre-swizzled source), single
// barrier/step, permuted-K QK^T, Q pre-scaled, branch-gated causal mask,
// lazy defer-max softmax.
__global__ __launch_bounds__(512, 2) void attn_fwd(const bf16* __restrict__ qkv,
                                                   bf16* __restrict__ O) {
  __shared__ __align__(16) char Kl[2][64 * 128];
  __shared__ __align__(16) char Vt[2][64 * 128];
  const int tid = threadIdx.x;
  const int lane = tid & 63, w = tid >> 6;
  const int g = lane >> 4, l15 = lane & 15;
  const int bh = blockIdx.x;
  const int bx = blockIdx.y;
  const int b = bh >> 4, hh = bh & 15;
  const size_t tokbase = (size_t)b * 2048;

  const bf16* kbase = qkv + tokbase * 3072 + 1024 + hh * 64;
  const bf16* vbase = qkv + tokbase * 3072 + 2048 + hh * 64;
  const int kperm = 8 * (l15 >> 2) + (l15 & 3);

  const int kr8 = tid >> 3, kc = tid & 7;
  const int kswz = (kr8 & 3) | ((kr8 & 8) >> 1);
  const bf16* kSrc = kbase + (size_t)kr8 * 3072 + 8 * (kc ^ kswz);

  const bool vstage = tid < 256;
  const int t2 = tid & 255;
  const int vrg = t2 >> 4, vds = (t2 & 15) * 4;

  union U4 { ushort4 v; u16 a[4]; };
  U4 vr[4];

  auto prefetchV = [&](int k0n) {
    if (vstage) {
#pragma unroll
      for (int i4 = 0; i4 < 4; i4++)
        vr[i4].v = *(const ushort4*)(vbase + (size_t)(k0n + 4 * vrg + i4) * 3072 + vds);
    }
  };
  auto gloadK = [&](int k0n, int buf) {
    GLOAD_LDS(kSrc + (size_t)k0n * 3072, Kl[buf] + w * 1024);
  };

  prefetchV(0);
  gloadK(0, 0);
  int cur = 0;

  for (int half = 0; half < 2; half++) {
    const int xT = half ? (15 - bx) : bx;
    const int q0 = xT * 128;
    const int qw0 = q0 + 16 * w;
    const int qi = qw0 + l15;
    const int kend = q0 + 128;

    const bf16* qptr = qkv + (tokbase + qw0 + l15) * 3072 + hh * 64 + 8 * g;
    const bf16x8 qf0 = *(const bf16x8*)(qptr);
    const bf16x8 qf1 = *(const bf16x8*)(qptr + 32);

    f32x4 ot[4] = {};
    float m_i = -INFINITY, l_i = 0.0f;

    for (int k0 = 0; k0 < kend; k0 += 64) {
      char* Kc = Kl[cur];
      char* Vc = Vt[cur];
      if (vstage) {
#pragma unroll
        for (int dj = 0; dj < 4; dj++) {
          const int d = vds + dj;
          u32 lo = (u32)vr[0].a[dj] | ((u32)vr[1].a[dj] << 16);
          u32 hi2 = (u32)vr[2].a[dj] | ((u32)vr[3].a[dj] << 16);
          const int boff = d * 128 + ((((vrg >> 1) ^ ((d >> 1) & 7)) << 4)) + ((vrg & 1) << 3);
          *(uint2*)(Vc + boff) = make_uint2(lo, hi2);
        }
      }
      __syncthreads();

      const int k0n = (k0 + 64 < kend) ? k0 + 64 : 0;
      prefetchV(k0n);
      gloadK(k0n, cur ^ 1);

      if (k0 <= qw0 + 15) {
        const bool lastT = (k0 + 63 > qw0);
        const int npair = lastT ? (((qw0 + 15 - k0) >> 5) + 1) : 2;

        f32x4 st[4];
#pragma unroll
        for (int ip = 0; ip < 2; ip++)
          if (ip < npair) {
#pragma unroll
            for (int h2 = 0; h2 < 2; h2++) {
              const int kr = 32 * ip + 4 * h2 + kperm;
              const int swzk = (kr & 3) | ((kr & 8) >> 1);
              const char* kro = Kc + kr * 128;
              bf16x8 ka = *(const bf16x8*)(kro + ((g ^ swzk) << 4));
              bf16x8 kb = *(const bf16x8*)(kro + (((g | 4) ^ swzk) << 4));
              f32x4 z = {};
              z = MFMA_BF16(ka, qf0, z, 0, 0, 0);
              st[2 * ip + h2] = MFMA_BF16(kb, qf1, z, 0, 0, 0);
            }
          }

        float p[4][4];
#pragma unroll
        for (int ip = 0; ip < 2; ip++)
          if (ip < npair)
#pragma unroll
            for (int h2 = 0; h2 < 2; h2++)
#pragma unroll
              for (int r = 0; r < 4; r++)
                p[2 * ip + h2][r] = (float)st[2 * ip + h2][r];
        if (lastT) {
#pragma unroll
          for (int ip = 0; ip < 2; ip++)
            if (ip < npair)
#pragma unroll
              for (int h2 = 0; h2 < 2; h2++)
#pragma unroll
                for (int r = 0; r < 4; r++) {
                  const int kk = k0 + 32 * ip + 8 * g + 4 * h2 + r;
                  if (kk > qi) p[2 * ip + h2][r] = -INFINITY;
                }
        }
        float mt = -INFINITY;
#pragma unroll
        for (int ip = 0; ip < 2; ip++)
          if (ip < npair)
#pragma unroll
            for (int h2 = 0; h2 < 2; h2++)
#pragma unroll
              for (int r = 0; r < 4; r++) mt = fmaxf(mt, p[2 * ip + h2][r]);

        if (!__all(mt - m_i <= 8.0f)) {
          mt = fmaxf(mt, __shfl_xor(mt, 16, 64));
          mt = fmaxf(mt, __shfl_xor(mt, 32, 64));
          const float m_new = fmaxf(m_i, mt);
          const float alpha = __expf(m_i - m_new);
          l_i *= alpha;
#pragma unroll
          for (int dt = 0; dt < 4; dt++)
#pragma unroll
            for (int r = 0; r < 4; r++) ot[dt][r] *= alpha;
          m_i = m_new;
        }
        float sum = 0.0f;
#pragma unroll
        for (int ip = 0; ip < 2; ip++)
          if (ip < npair) {
#pragma unroll
            for (int h2 = 0; h2 < 2; h2++)
#pragma unroll
              for (int r = 0; r < 4; r++) {
                float e = __expf(p[2 * ip + h2][r] - m_i);
                p[2 * ip + h2][r] = e;
                sum += e;
              }
          }
        l_i += sum;

#pragma unroll
        for (int ip = 0; ip < 2; ip++)
          if (ip < npair) {
            bf16x8 pf;
#pragma unroll
            for (int h2 = 0; h2 < 2; h2++)
#pragma unroll
              for (int r = 0; r < 4; r++) pf[4 * h2 + r] = (bf16)p[2 * ip + h2][r];
#pragma unroll
            for (int dt = 0; dt < 4; dt++) {
              const bf16x8 vf = *(const bf16x8*)(
                  Vc + (dt * 16 + l15) * 128 + (((4 * ip + g) ^ (l15 >> 1)) << 4));
              ot[dt] = MFMA_BF16(vf, pf, ot[dt], 0, 0, 0);
            }
          }
      }
      cur ^= 1;
    }

    l_i += __shfl_xor(l_i, 16, 64);
    l_i += __shfl_xor(l_i, 32, 64);
    const float inv = 1.0f / l_i;
    bf16* obase = O + (tokbase + qw0 + l15) * 1024 + hh * 64;
#pragma unroll
    for (int dt = 0; dt < 4; dt++) {
      bf16x4 ov;
#pragma unroll
      for (int r = 0; r < 4; r++) ov[r] = (bf16)(ot[dt][r] * inv);
      *(bf16x4*)(obase + dt * 16 + 4 * g) = ov;
    }
  }
}

// ---------------------------------------------------------------- launch
extern "C" void kernel_launch(void* const* d_in, const int* in_sizes, int n_in,
                              void* d_out, int out_size, void* d_ws, size_t ws_size,
                              hipStream_t stream) {
  const float* x = (const float*)d_in[0];
  const float* w_qkv = (const float*)d_in[1];
  const float* w_out = (const float*)d_in[2];
  const float* w_ff1 = (const float*)d_in[3];
  const float* w_ff2 = (const float*)d_in[4];
  float* out = (float*)d_out;

  char* ws = (char*)d_ws;
  size_t off = 0;
  auto alloc = [&](size_t bytes) {
    void* p = ws + off;
    off += (bytes + 255) & ~(size_t)255;
    return p;
  };
  const size_t M = 8192;
  bf16* X16   = (bf16*)alloc(M * 1024 * 2);
  bf16* WqkvT = (bf16*)alloc(3072ull * 1024 * 2);
  bf16* WoutT = (bf16*)alloc(1024ull * 1024 * 2);
  bf16* Wff1T = (bf16*)alloc(4096ull * 1024 * 2);
  bf16* Wff2T = (bf16*)alloc(1024ull * 4096 * 2);
  bf16* QKV   = (bf16*)alloc(M * 3072 * 2);
  bf16* Obuf  = (bf16*)alloc(M * 1024 * 2);
  bf16* x1b   = (bf16*)alloc(M * 1024 * 2);
  bf16* Hbuf  = (bf16*)alloc(M * 4096 * 2);

  cvt_f32_bf16<<<8192, 256, 0, stream>>>(x, X16, 8192 * 1024);
  transpose_w<<<dim3(3072 / 32, 1024 / 32), 256, 0, stream>>>(w_qkv, WqkvT, 1024, 3072);
  transpose_w<<<dim3(1024 / 32, 1024 / 32), 256, 0, stream>>>(w_out, WoutT, 1024, 1024);
  transpose_w<<<dim3(4096 / 32, 1024 / 32), 256, 0, stream>>>(w_ff1, Wff1T, 1024, 4096);
  transpose_w<<<dim3(1024 / 32, 4096 / 32), 256, 0, stream>>>(w_ff2, Wff2T, 4096, 1024);

  // grids: (M/128)*(N/128) = 64*NT blocks, XCD-chunked + supertile order
  gemm_bt<0><<<64 * 24, 256, 0, stream>>>(X16, WqkvT, QKV, nullptr, nullptr, nullptr, 1024, 3072);
  attn_fwd<<<dim3(64, 8), 512, 0, stream>>>(QKV, Obuf);
  gemm_bt<1><<<64 * 8, 256, 0, stream>>>(Obuf, WoutT, x1b, nullptr, x, nullptr, 1024, 1024);
  gemm_bt<2><<<64 * 32, 256, 0, stream>>>(x1b, Wff1T, Hbuf, nullptr, nullptr, nullptr, 1024, 4096);
  gemm_bt<3><<<64 * 8, 256, 0, stream>>>(Hbuf, Wff2T, nullptr, out, nullptr, x1b, 4096, 1024);
}